// Round 5
// baseline (113.909 us; speedup 1.0000x reference)
//
#include <hip/hip_runtime.h>
#include <hip/hip_bf16.h>
#include <stdint.h>

#define NE 8
#define DK 1024
#define FN 1024
#define NTOK 8192

#define BM 256
#define BN 256
#define BK 64
#define NIT (DK / BK)

#define HB 32
#define EPB (NTOK * 2 / HB)

typedef __attribute__((ext_vector_type(4))) float f32x4;
typedef __attribute__((ext_vector_type(8))) short short8;
typedef __attribute__((ext_vector_type(4))) short short4v;

__device__ __forceinline__ unsigned short f2bf(float f) {
    union { float f; unsigned u; } v; v.f = f;
    unsigned r = v.u;
    unsigned lsb = (r >> 16) & 1u;
    r += 0x7fffu + lsb;
    return (unsigned short)(r >> 16);
}
__device__ __forceinline__ float bf2f(unsigned short u) {
    union { unsigned u; float f; } v; v.u = ((unsigned)u) << 16;
    return v.f;
}

// ---------------- gating + x -> bf16 conversion (one wave per token) ---------
__global__ __launch_bounds__(256) void k_gate(const float* __restrict__ x,
    const float* __restrict__ Wg, const float* __restrict__ bg,
    unsigned short* __restrict__ xb, int* __restrict__ meta_e,
    float* __restrict__ meta_w)
{
    const int lane = threadIdx.x & 63;
    const int t = blockIdx.x * 4 + (threadIdx.x >> 6);

    const f32x4* xr = (const f32x4*)(x + (size_t)t * DK);
    f32x4 xv[4];
#pragma unroll
    for (int c = 0; c < 4; ++c) xv[c] = xr[lane + 64 * c];

    short4v* xbo = (short4v*)(xb + (size_t)t * DK);
#pragma unroll
    for (int c = 0; c < 4; ++c) {
        short4v b;
        b.x = (short)f2bf(xv[c].x); b.y = (short)f2bf(xv[c].y);
        b.z = (short)f2bf(xv[c].z); b.w = (short)f2bf(xv[c].w);
        xbo[lane + 64 * c] = b;
    }

    float acc[NE];
#pragma unroll
    for (int e = 0; e < NE; ++e) {
        const f32x4* wr = (const f32x4*)(Wg + e * DK);
        float a = 0.f;
#pragma unroll
        for (int c = 0; c < 4; ++c) {
            f32x4 wv = wr[lane + 64 * c];
            a += xv[c].x * wv.x + xv[c].y * wv.y + xv[c].z * wv.z + xv[c].w * wv.w;
        }
        acc[e] = a;
    }
#pragma unroll
    for (int e = 0; e < NE; ++e) {
        float a = acc[e];
#pragma unroll
        for (int off = 32; off > 0; off >>= 1) a += __shfl_xor(a, off, 64);
        acc[e] = a;
    }
    if (lane == 0) {
        float v[NE];
#pragma unroll
        for (int e = 0; e < NE; ++e) v[e] = acc[e] + bg[e];
        int b0 = 0; float m0 = v[0];
#pragma unroll
        for (int e = 1; e < NE; ++e) if (v[e] > m0) { m0 = v[e]; b0 = e; }
        int b1 = -1; float m1 = -3.4e38f;
#pragma unroll
        for (int e = 0; e < NE; ++e) if (e != b0 && v[e] > m1) { m1 = v[e]; b1 = e; }
        float r = expf(m1 - m0);
        float s = 1.f + r;
        meta_e[2 * t] = b0; meta_e[2 * t + 1] = b1;
        meta_w[2 * t] = 1.f / s; meta_w[2 * t + 1] = r / s;
    }
}

// ---------------- W -> bf16 ---------------------------------------------------
__global__ __launch_bounds__(256) void k_convw(const float* __restrict__ W,
                                               unsigned short* __restrict__ Wb)
{
    int i = blockIdx.x * 256 + threadIdx.x;
    f32x4 v = ((const f32x4*)W)[i];
    short4v b;
    b.x = (short)f2bf(v.x); b.y = (short)f2bf(v.y);
    b.z = (short)f2bf(v.z); b.w = (short)f2bf(v.w);
    ((short4v*)Wb)[i] = b;
}

// ---------------- per-block histogram (LDS atomics only) ---------------------
__global__ __launch_bounds__(256) void k_hist(const int* __restrict__ meta_e,
                                              int* __restrict__ blockcnt)
{
    __shared__ int lh[NE];
    if (threadIdx.x < NE) lh[threadIdx.x] = 0;
    __syncthreads();
    int base = blockIdx.x * EPB;
#pragma unroll
    for (int k = 0; k < EPB / 256; ++k)
        atomicAdd(&lh[meta_e[base + k * 256 + threadIdx.x]], 1);
    __syncthreads();
    if (threadIdx.x < NE) blockcnt[blockIdx.x * NE + threadIdx.x] = lh[threadIdx.x];
}

// ---------------- scan: expert segs + per-block bases ------------------------
__global__ void k_scan(const int* __restrict__ blockcnt, int* __restrict__ seg,
                       int* __restrict__ base)
{
    __shared__ int pre[HB][NE];
    __shared__ int colsum[NE];
    __shared__ int segstart[NE];
    int tid = threadIdx.x;
    if (tid < NE) {
        int run = 0;
        for (int b = 0; b < HB; ++b) { pre[b][tid] = run; run += blockcnt[b * NE + tid]; }
        colsum[tid] = run;
    }
    __syncthreads();
    if (tid == 0) {
        int s = 0;
        for (int e = 0; e < NE; ++e) { segstart[e] = s; seg[e] = s; s += colsum[e]; }
        seg[NE] = s;
    }
    __syncthreads();
    for (int i = tid; i < HB * NE; i += 64) {
        int b = i / NE, e = i % NE;
        base[i] = segstart[e] + pre[b][e];
    }
}

// ---------------- scatter: ridx[p] = 2t+k (orig slot), rw[p] = weight --------
__global__ __launch_bounds__(256) void k_scatter(const int* __restrict__ meta_e,
    const float* __restrict__ meta_w, const int* __restrict__ base,
    int* __restrict__ ridx, float* __restrict__ rw)
{
    __shared__ int lh[NE];
    __shared__ int bb[NE];
    if (threadIdx.x < NE) {
        lh[threadIdx.x] = 0;
        bb[threadIdx.x] = base[blockIdx.x * NE + threadIdx.x];
    }
    __syncthreads();
    int bs = blockIdx.x * EPB;
#pragma unroll
    for (int k = 0; k < EPB / 256; ++k) {
        int i = bs + k * 256 + threadIdx.x;
        int e = meta_e[i];
        int r = atomicAdd(&lh[e], 1);
        int p = bb[e] + r;
        ridx[p] = i;
        rw[p] = meta_w[i];
    }
}

// ---------------- grouped GEMM, 256x256, counted-vmcnt 2-phase pipeline ------
// 8 waves (2M x 4N), per-wave 128x64 output, LDS 128KB (2 dbuf x (A 32K + B 32K)).
// 1D grid, XCD-aware: expert = bid & 7 (blocks round-robin XCDs -> each XCD's
// L2 holds one expert's 2MB W panel).
// MODE 0: fp32 atomicAdd into out.  MODE 1: bf16 stores to yw.  MODE 2: f32 yw.
template <int MODE>
__global__ __launch_bounds__(512, 2) void k_gemm(const unsigned short* __restrict__ xb,
    const unsigned short* __restrict__ Wb, const float* __restrict__ be,
    const int* __restrict__ seg, const int* __restrict__ ridx,
    const float* __restrict__ rw, float* __restrict__ out, void* __restrict__ ywv)
{
    __shared__ unsigned short Lds[2 * 2 * BM * BK];   // 128 KB

    const int bid = blockIdx.x;
    const int e = bid & 7;
    const int n0 = ((bid >> 3) & 3) * BN;
    const int s0 = seg[e];
    const int L = seg[e + 1] - s0;
    const int m0 = (bid >> 5) * BM;
    if (m0 >= L) return;

    const int tid = threadIdx.x;
    const int lane = tid & 63;
    const int wid = tid >> 6;
    const int wm = wid >> 2, wn = wid & 3;   // 2 x 4 wave grid

    // staging: call c covers rows c*64 + tid/8, col-block tid%8 (16B units)
    const int srow = tid >> 3;
    const int scb = tid & 7;
    const unsigned short* asrc[4];
    const unsigned short* bsrc[4];
#pragma unroll
    for (int c = 0; c < 4; ++c) {
        int r = c * 64 + srow;
        int cbs = scb ^ (r & 7);            // swizzle via pre-swizzled source
        int idx = m0 + r; if (idx >= L) idx = L - 1;
        asrc[c] = xb + (size_t)(ridx[s0 + idx] >> 1) * DK + cbs * 8;
        bsrc[c] = Wb + ((size_t)e * FN + n0 + r) * DK + cbs * 8;
    }

    char* LB = (char*)Lds;                   // buf stride 65536; B at +32768

    f32x4 acc[8][4];
#pragma unroll
    for (int i = 0; i < 8; ++i)
#pragma unroll
        for (int j = 0; j < 4; ++j) acc[i][j] = f32x4{0.f, 0.f, 0.f, 0.f};

    const int frow = lane & 15;
    const int fq = lane >> 4;
    int a_off[8][2], b_off[4][2];
#pragma unroll
    for (int mi = 0; mi < 8; ++mi) {
        int row = wm * 128 + mi * 16 + frow;
#pragma unroll
        for (int kk = 0; kk < 2; ++kk) {
            int cb = (kk * 4 + fq) ^ (row & 7);
            a_off[mi][kk] = row * 128 + cb * 16;
        }
    }
#pragma unroll
    for (int ni = 0; ni < 4; ++ni) {
        int row = wn * 64 + ni * 16 + frow;
#pragma unroll
        for (int kk = 0; kk < 2; ++kk) {
            int cb = (kk * 4 + fq) ^ (row & 7);
            b_off[ni][kk] = 32768 + row * 128 + cb * 16;
        }
    }

    auto STAGE = [&](int buf, int kt) {
        const int ko = kt * BK;
        char* dstA = LB + buf * 65536 + wid * 1024;
        char* dstB = dstA + 32768;
#pragma unroll
        for (int c = 0; c < 4; ++c)
            __builtin_amdgcn_global_load_lds(
                (const __attribute__((address_space(1))) void*)(asrc[c] + ko),
                (__attribute__((address_space(3))) void*)(dstA + c * 8192),
                16, 0, 0);
#pragma unroll
        for (int c = 0; c < 4; ++c)
            __builtin_amdgcn_global_load_lds(
                (const __attribute__((address_space(1))) void*)(bsrc[c] + ko),
                (__attribute__((address_space(3))) void*)(dstB + c * 8192),
                16, 0, 0);
    };

    auto COMPUTE = [&](int buf) {
        const char* base = LB + buf * 65536;
#pragma unroll
        for (int kk = 0; kk < 2; ++kk) {
            short8 af[8], bfr[4];
#pragma unroll
            for (int mi = 0; mi < 8; ++mi) af[mi] = *(const short8*)(base + a_off[mi][kk]);
#pragma unroll
            for (int ni = 0; ni < 4; ++ni) bfr[ni] = *(const short8*)(base + b_off[ni][kk]);
#pragma unroll
            for (int mi = 0; mi < 8; ++mi)
#pragma unroll
                for (int ni = 0; ni < 4; ++ni)
                    acc[mi][ni] = __builtin_amdgcn_mfma_f32_16x16x32_bf16(
                        af[mi], bfr[ni], acc[mi][ni], 0, 0, 0);
        }
    };

    // T4 counted-vmcnt pipeline: wait only for the PREVIOUS tile's 8 loads;
    // the 8 just-issued next-tile loads stay in flight across the barrier.
    STAGE(0, 0);
    __builtin_amdgcn_sched_barrier(0);

    for (int kt = 0; kt < NIT; ++kt) {
        const int cur = kt & 1;
        if (kt + 1 < NIT) {
            STAGE(cur ^ 1, kt + 1);
            __builtin_amdgcn_sched_barrier(0);
            asm volatile("s_waitcnt vmcnt(8)" ::: "memory");
        } else {
            asm volatile("s_waitcnt vmcnt(0)" ::: "memory");
        }
        __builtin_amdgcn_s_barrier();           // buf cur fully populated (all waves)
        __builtin_amdgcn_sched_barrier(0);
        COMPUTE(cur);
        __builtin_amdgcn_sched_barrier(0);
        __builtin_amdgcn_s_barrier();           // all reads of cur done before overwrite
    }

    // epilogue: D col = lane&15, row = (lane>>4)*4 + j
    float bias_n[4];
#pragma unroll
    for (int ni = 0; ni < 4; ++ni)
        bias_n[ni] = be[e * FN + n0 + wn * 64 + ni * 16 + frow];

    const int fq4 = fq * 4;
#pragma unroll
    for (int mi = 0; mi < 8; ++mi) {
        int rl = m0 + wm * 128 + mi * 16 + fq4;
#pragma unroll
        for (int j = 0; j < 4; ++j) {
            int idx = rl + j;
            if (idx < L) {
                float w = rw[s0 + idx];
                int oi = ridx[s0 + idx];
                if (MODE == 0) {
                    float* orow = out + (size_t)(oi >> 1) * FN + n0 + wn * 64 + frow;
#pragma unroll
                    for (int ni = 0; ni < 4; ++ni)
                        atomicAdd(orow + ni * 16, w * (acc[mi][ni][j] + bias_n[ni]));
                } else if (MODE == 1) {
                    unsigned short* yrow = (unsigned short*)ywv + (size_t)oi * FN + n0 + wn * 64 + frow;
#pragma unroll
                    for (int ni = 0; ni < 4; ++ni)
                        yrow[ni * 16] = f2bf(w * (acc[mi][ni][j] + bias_n[ni]));
                } else {
                    float* yrow = (float*)ywv + (size_t)oi * FN + n0 + wn * 64 + frow;
#pragma unroll
                    for (int ni = 0; ni < 4; ++ni)
                        yrow[ni * 16] = w * (acc[mi][ni][j] + bias_n[ni]);
                }
            }
        }
    }
}

// ---------------- combine: out[t] = yw[2t] + yw[2t+1] ------------------------
__global__ __launch_bounds__(256) void k_combine_bf(const unsigned short* __restrict__ yw,
                                                    float* __restrict__ out)
{
    int t = blockIdx.x;
    const short4v* r0 = (const short4v*)(yw + (size_t)(2 * t) * FN);
    const short4v* r1 = (const short4v*)(yw + (size_t)(2 * t + 1) * FN);
    f32x4* o = (f32x4*)(out + (size_t)t * FN);
    int i = threadIdx.x;
    short4v a = r0[i], b = r1[i];
    f32x4 v;
    v.x = bf2f((unsigned short)a.x) + bf2f((unsigned short)b.x);
    v.y = bf2f((unsigned short)a.y) + bf2f((unsigned short)b.y);
    v.z = bf2f((unsigned short)a.z) + bf2f((unsigned short)b.z);
    v.w = bf2f((unsigned short)a.w) + bf2f((unsigned short)b.w);
    o[i] = v;
}

__global__ __launch_bounds__(256) void k_combine_f32(const float* __restrict__ yw,
                                                     float* __restrict__ out)
{
    int t = blockIdx.x;
    const f32x4* r0 = (const f32x4*)(yw + (size_t)(2 * t) * FN);
    const f32x4* r1 = (const f32x4*)(yw + (size_t)(2 * t + 1) * FN);
    f32x4* o = (f32x4*)(out + (size_t)t * FN);
    int i = threadIdx.x;
    o[i] = r0[i] + r1[i];
}

extern "C" void kernel_launch(void* const* d_in, const int* in_sizes, int n_in,
                              void* d_out, int out_size, void* d_ws, size_t ws_size,
                              hipStream_t stream)
{
    const float* x   = (const float*)d_in[0];
    const float* We  = (const float*)d_in[1];
    const float* beb = (const float*)d_in[2];
    const float* Wg  = (const float*)d_in[3];
    const float* bg  = (const float*)d_in[4];
    float* out = (float*)d_out;

    char* ws = (char*)d_ws;
    unsigned short* xb = (unsigned short*)ws;                        // 16 MB
    unsigned short* Wb = (unsigned short*)(ws + (size_t)(16 << 20)); // 16 MB
    size_t off = (size_t)(32 << 20);
    int*   seg      = (int*)(ws + off);   off += 256;
    int*   blockcnt = (int*)(ws + off);   off += HB * NE * 4;
    int*   basebuf  = (int*)(ws + off);   off += HB * NE * 4;
    int*   meta_e   = (int*)(ws + off);   off += (size_t)NTOK * 2 * 4;
    float* meta_w   = (float*)(ws + off); off += (size_t)NTOK * 2 * 4;
    int*   ridxb    = (int*)(ws + off);   off += (size_t)NTOK * 2 * 4;
    float* rwb      = (float*)(ws + off); off += (size_t)NTOK * 2 * 4;
    void*  yw       = (void*)(ws + ((off + 255) & ~(size_t)255));
    size_t yw_base  = (size_t)((off + 255) & ~(size_t)255);

    // pick epilogue mode from available scratch (host-side, deterministic).
    int mode;
    if (ws_size >= yw_base + (size_t)NTOK * 2 * FN * 2) mode = 1;       // bf16 yw (32 MB)
    else if (ws_size >= yw_base + (size_t)NTOK * 2 * FN * 4) mode = 2;  // f32 yw (64 MB)
    else mode = 0;                                                      // atomic fallback

    k_gate<<<NTOK / 4, 256, 0, stream>>>(x, Wg, bg, xb, meta_e, meta_w);
    k_convw<<<(NE * FN * DK / 4) / 256, 256, 0, stream>>>(We, Wb);
    k_hist<<<HB, 256, 0, stream>>>(meta_e, blockcnt);
    k_scan<<<1, 64, 0, stream>>>(blockcnt, seg, basebuf);
    k_scatter<<<HB, 256, 0, stream>>>(meta_e, meta_w, basebuf, ridxb, rwb);

    const int nblk = NE * (FN / BN) * 32;   // 8 experts x 4 n-tiles x 32 m-tiles
    if (mode == 1) {
        k_gemm<1><<<nblk, 512, 0, stream>>>(xb, Wb, beb, seg, ridxb, rwb, out, yw);
        k_combine_bf<<<NTOK, 256, 0, stream>>>((const unsigned short*)yw, out);
    } else if (mode == 2) {
        k_gemm<2><<<nblk, 512, 0, stream>>>(xb, Wb, beb, seg, ridxb, rwb, out, yw);
        k_combine_f32<<<NTOK, 256, 0, stream>>>((const float*)yw, out);
    } else {
        hipMemsetAsync(d_out, 0, (size_t)NTOK * FN * 4, stream);
        k_gemm<0><<<nblk, 512, 0, stream>>>(xb, Wb, beb, seg, ridxb, rwb, out, yw);
    }
}

// Round 6
// 111.184 us; speedup vs baseline: 1.0245x; 1.0245x over previous
//
#include <hip/hip_runtime.h>
#include <hip/hip_bf16.h>
#include <stdint.h>

#define NE 8
#define DK 1024
#define FN 1024
#define NTOK 8192

#define BM 256
#define BN 256
#define BK 64
#define NIT (DK / BK)

#define HB 32
#define EPB (NTOK * 2 / HB)

typedef __attribute__((ext_vector_type(4))) float f32x4;
typedef __attribute__((ext_vector_type(8))) short short8;
typedef __attribute__((ext_vector_type(4))) short short4v;

__device__ __forceinline__ unsigned short f2bf(float f) {
    union { float f; unsigned u; } v; v.f = f;
    unsigned r = v.u;
    unsigned lsb = (r >> 16) & 1u;
    r += 0x7fffu + lsb;
    return (unsigned short)(r >> 16);
}
__device__ __forceinline__ float bf2f(unsigned short u) {
    union { unsigned u; float f; } v; v.u = ((unsigned)u) << 16;
    return v.f;
}

// ---------------- gating + x -> bf16 conversion (one wave per token) ---------
__global__ __launch_bounds__(256) void k_gate(const float* __restrict__ x,
    const float* __restrict__ Wg, const float* __restrict__ bg,
    unsigned short* __restrict__ xb, int* __restrict__ meta_e,
    float* __restrict__ meta_w)
{
    const int lane = threadIdx.x & 63;
    const int t = blockIdx.x * 4 + (threadIdx.x >> 6);

    const f32x4* xr = (const f32x4*)(x + (size_t)t * DK);
    f32x4 xv[4];
#pragma unroll
    for (int c = 0; c < 4; ++c) xv[c] = xr[lane + 64 * c];

    short4v* xbo = (short4v*)(xb + (size_t)t * DK);
#pragma unroll
    for (int c = 0; c < 4; ++c) {
        short4v b;
        b.x = (short)f2bf(xv[c].x); b.y = (short)f2bf(xv[c].y);
        b.z = (short)f2bf(xv[c].z); b.w = (short)f2bf(xv[c].w);
        xbo[lane + 64 * c] = b;
    }

    float acc[NE];
#pragma unroll
    for (int e = 0; e < NE; ++e) {
        const f32x4* wr = (const f32x4*)(Wg + e * DK);
        float a = 0.f;
#pragma unroll
        for (int c = 0; c < 4; ++c) {
            f32x4 wv = wr[lane + 64 * c];
            a += xv[c].x * wv.x + xv[c].y * wv.y + xv[c].z * wv.z + xv[c].w * wv.w;
        }
        acc[e] = a;
    }
#pragma unroll
    for (int e = 0; e < NE; ++e) {
        float a = acc[e];
#pragma unroll
        for (int off = 32; off > 0; off >>= 1) a += __shfl_xor(a, off, 64);
        acc[e] = a;
    }
    if (lane == 0) {
        float v[NE];
#pragma unroll
        for (int e = 0; e < NE; ++e) v[e] = acc[e] + bg[e];
        int b0 = 0; float m0 = v[0];
#pragma unroll
        for (int e = 1; e < NE; ++e) if (v[e] > m0) { m0 = v[e]; b0 = e; }
        int b1 = -1; float m1 = -3.4e38f;
#pragma unroll
        for (int e = 0; e < NE; ++e) if (e != b0 && v[e] > m1) { m1 = v[e]; b1 = e; }
        float r = expf(m1 - m0);
        float s = 1.f + r;
        meta_e[2 * t] = b0; meta_e[2 * t + 1] = b1;
        meta_w[2 * t] = 1.f / s; meta_w[2 * t + 1] = r / s;
    }
}

// ---------------- W -> bf16 ---------------------------------------------------
__global__ __launch_bounds__(256) void k_convw(const float* __restrict__ W,
                                               unsigned short* __restrict__ Wb)
{
    int i = blockIdx.x * 256 + threadIdx.x;
    f32x4 v = ((const f32x4*)W)[i];
    short4v b;
    b.x = (short)f2bf(v.x); b.y = (short)f2bf(v.y);
    b.z = (short)f2bf(v.z); b.w = (short)f2bf(v.w);
    ((short4v*)Wb)[i] = b;
}

// ---------------- per-block histogram (LDS atomics only) ---------------------
__global__ __launch_bounds__(256) void k_hist(const int* __restrict__ meta_e,
                                              int* __restrict__ blockcnt)
{
    __shared__ int lh[NE];
    if (threadIdx.x < NE) lh[threadIdx.x] = 0;
    __syncthreads();
    int base = blockIdx.x * EPB;
#pragma unroll
    for (int k = 0; k < EPB / 256; ++k)
        atomicAdd(&lh[meta_e[base + k * 256 + threadIdx.x]], 1);
    __syncthreads();
    if (threadIdx.x < NE) blockcnt[blockIdx.x * NE + threadIdx.x] = lh[threadIdx.x];
}

// ---------------- scan: expert segs + per-block bases ------------------------
__global__ void k_scan(const int* __restrict__ blockcnt, int* __restrict__ seg,
                       int* __restrict__ base)
{
    __shared__ int pre[HB][NE];
    __shared__ int colsum[NE];
    __shared__ int segstart[NE];
    int tid = threadIdx.x;
    if (tid < NE) {
        int run = 0;
        for (int b = 0; b < HB; ++b) { pre[b][tid] = run; run += blockcnt[b * NE + tid]; }
        colsum[tid] = run;
    }
    __syncthreads();
    if (tid == 0) {
        int s = 0;
        for (int e = 0; e < NE; ++e) { segstart[e] = s; seg[e] = s; s += colsum[e]; }
        seg[NE] = s;
    }
    __syncthreads();
    for (int i = tid; i < HB * NE; i += 64) {
        int b = i / NE, e = i % NE;
        base[i] = segstart[e] + pre[b][e];
    }
}

// ---------------- scatter: ridx[p] = 2t+k (orig slot), rw[p] = weight --------
__global__ __launch_bounds__(256) void k_scatter(const int* __restrict__ meta_e,
    const float* __restrict__ meta_w, const int* __restrict__ base,
    int* __restrict__ ridx, float* __restrict__ rw)
{
    __shared__ int lh[NE];
    __shared__ int bb[NE];
    if (threadIdx.x < NE) {
        lh[threadIdx.x] = 0;
        bb[threadIdx.x] = base[blockIdx.x * NE + threadIdx.x];
    }
    __syncthreads();
    int bs = blockIdx.x * EPB;
#pragma unroll
    for (int k = 0; k < EPB / 256; ++k) {
        int i = bs + k * 256 + threadIdx.x;
        int e = meta_e[i];
        int r = atomicAdd(&lh[e], 1);
        int p = bb[e] + r;
        ridx[p] = i;
        rw[p] = meta_w[i];
    }
}

// ---------------- grouped GEMM, 256x256, 8-phase counted-vmcnt pipeline ------
// 8 waves (2M x 4N). Halves = {A,B} x {K0-31, K32-63}; one half staged/phase;
// gates vmcnt(4) at ph0/ph2 only (in-order retire: oldest 2 halves landed).
// LDS per buf: A kh0 @0, A kh1 @16K, B kh0 @32K, B kh1 @48K; 2 bufs = 128 KB.
// Each half: [256 rows][32 K] at row stride 64B, slot swizzle s^( (r>>1)&3 ).
// MODE 0: fp32 atomicAdd into out.  MODE 1: bf16 stores to yw.  MODE 2: f32 yw.
template <int MODE>
__global__ __launch_bounds__(512, 2) void k_gemm(const unsigned short* __restrict__ xb,
    const unsigned short* __restrict__ Wb, const float* __restrict__ be,
    const int* __restrict__ seg, const int* __restrict__ ridx,
    const float* __restrict__ rw, float* __restrict__ out, void* __restrict__ ywv)
{
    __shared__ unsigned short Lds[2 * 2 * BM * BK];   // 128 KB

    const int bid = blockIdx.x;
    const int e = bid & 7;
    const int n0 = ((bid >> 3) & 3) * BN;
    const int s0 = seg[e];
    const int L = seg[e + 1] - s0;
    const int m0 = (bid >> 5) * BM;
    if (m0 >= L) return;

    const int tid = threadIdx.x;
    const int lane = tid & 63;
    const int wid = tid >> 6;
    const int wm = wid >> 2, wn = wid & 3;   // 2 x 4 wave grid

    // staging sources: call c covers rows c*128 + tid/4; 16B granule = orig
    // slot s_orig = (tid&3) ^ ((tid>>3)&3)  (pre-swizzled source, linear dest)
    const int so = ((tid & 3) ^ ((tid >> 3) & 3)) * 8;
    const unsigned short* asrc[2];
    const unsigned short* bsrc[2];
#pragma unroll
    for (int c = 0; c < 2; ++c) {
        int r = c * 128 + (tid >> 2);
        int idx = m0 + r; if (idx >= L) idx = L - 1;
        asrc[c] = xb + (size_t)(ridx[s0 + idx] >> 1) * DK + so;
        bsrc[c] = Wb + ((size_t)e * FN + n0 + r) * DK + so;
    }

    char* LB = (char*)Lds;

    f32x4 acc[8][4];
#pragma unroll
    for (int i = 0; i < 8; ++i)
#pragma unroll
        for (int j = 0; j < 4; ++j) acc[i][j] = f32x4{0.f, 0.f, 0.f, 0.f};

    const int frow = lane & 15;
    const int fq = lane >> 4;
    int a_off[8][2], b_off[4][2];
#pragma unroll
    for (int mi = 0; mi < 8; ++mi) {
        int r = wm * 128 + mi * 16 + frow;
        int sl = fq ^ ((r >> 1) & 3);
#pragma unroll
        for (int kk = 0; kk < 2; ++kk)
            a_off[mi][kk] = kk * 16384 + r * 64 + sl * 16;
    }
#pragma unroll
    for (int ni = 0; ni < 4; ++ni) {
        int r = wn * 64 + ni * 16 + frow;
        int sl = fq ^ ((r >> 1) & 3);
#pragma unroll
        for (int kk = 0; kk < 2; ++kk)
            b_off[ni][kk] = 32768 + kk * 16384 + r * 64 + sl * 16;
    }

    auto STAGE_A = [&](int buf, int kt, int kh) {
        const int ko = kt * 64 + kh * 32;
        char* dst = LB + buf * 65536 + kh * 16384 + wid * 1024;
        __builtin_amdgcn_global_load_lds(
            (const __attribute__((address_space(1))) void*)(asrc[0] + ko),
            (__attribute__((address_space(3))) void*)dst, 16, 0, 0);
        __builtin_amdgcn_global_load_lds(
            (const __attribute__((address_space(1))) void*)(asrc[1] + ko),
            (__attribute__((address_space(3))) void*)(dst + 8192), 16, 0, 0);
    };
    auto STAGE_B = [&](int buf, int kt, int kh) {
        const int ko = kt * 64 + kh * 32;
        char* dst = LB + buf * 65536 + 32768 + kh * 16384 + wid * 1024;
        __builtin_amdgcn_global_load_lds(
            (const __attribute__((address_space(1))) void*)(bsrc[0] + ko),
            (__attribute__((address_space(3))) void*)dst, 16, 0, 0);
        __builtin_amdgcn_global_load_lds(
            (const __attribute__((address_space(1))) void*)(bsrc[1] + ko),
            (__attribute__((address_space(3))) void*)(dst + 8192), 16, 0, 0);
    };

#define GATE4 do { asm volatile("s_waitcnt vmcnt(4)" ::: "memory"); \
                   __builtin_amdgcn_s_barrier(); \
                   __builtin_amdgcn_sched_barrier(0); } while (0)
#define GATE0 do { asm volatile("s_waitcnt vmcnt(0)" ::: "memory"); \
                   __builtin_amdgcn_s_barrier(); \
                   __builtin_amdgcn_sched_barrier(0); } while (0)
#define BARP  do { __builtin_amdgcn_s_barrier(); \
                   __builtin_amdgcn_sched_barrier(0); } while (0)

    // prologue: stage tile 0 (A-kh0, B-kh0, A-kh1, B-kh1) into buf 0
    STAGE_A(0, 0, 0); STAGE_B(0, 0, 0); STAGE_A(0, 0, 1); STAGE_B(0, 0, 1);

    for (int t = 0; t < NIT; ++t) {
        const int b = t & 1;
        const char* Cb = LB + b * 65536;
        const bool st = (t + 1 < NIT);

        // ---- phase 0: kk0, mi 0-3 (gate covers tile t kh0 halves) ----
        GATE4;
        short8 b0[4], a0[4];
#pragma unroll
        for (int ni = 0; ni < 4; ++ni) b0[ni] = *(const short8*)(Cb + b_off[ni][0]);
#pragma unroll
        for (int mi = 0; mi < 4; ++mi) a0[mi] = *(const short8*)(Cb + a_off[mi][0]);
        if (st) STAGE_A(b ^ 1, t + 1, 0);
        __builtin_amdgcn_s_setprio(1);
#pragma unroll
        for (int mi = 0; mi < 4; ++mi)
#pragma unroll
            for (int ni = 0; ni < 4; ++ni)
                acc[mi][ni] = __builtin_amdgcn_mfma_f32_16x16x32_bf16(
                    a0[mi], b0[ni], acc[mi][ni], 0, 0, 0);
        __builtin_amdgcn_s_setprio(0);

        // ---- phase 1: kk0, mi 4-7 ----
        BARP;
        short8 a1[4];
#pragma unroll
        for (int mi = 0; mi < 4; ++mi) a1[mi] = *(const short8*)(Cb + a_off[4 + mi][0]);
        if (st) STAGE_B(b ^ 1, t + 1, 0);
        __builtin_amdgcn_s_setprio(1);
#pragma unroll
        for (int mi = 0; mi < 4; ++mi)
#pragma unroll
            for (int ni = 0; ni < 4; ++ni)
                acc[4 + mi][ni] = __builtin_amdgcn_mfma_f32_16x16x32_bf16(
                    a1[mi], b0[ni], acc[4 + mi][ni], 0, 0, 0);
        __builtin_amdgcn_s_setprio(0);

        // ---- phase 2: kk1, mi 0-3 (gate covers tile t kh1 halves) ----
        if (st) { GATE4; } else { GATE0; }
        short8 b1[4], a2[4];
#pragma unroll
        for (int ni = 0; ni < 4; ++ni) b1[ni] = *(const short8*)(Cb + b_off[ni][1]);
#pragma unroll
        for (int mi = 0; mi < 4; ++mi) a2[mi] = *(const short8*)(Cb + a_off[mi][1]);
        if (st) STAGE_A(b ^ 1, t + 1, 1);
        __builtin_amdgcn_s_setprio(1);
#pragma unroll
        for (int mi = 0; mi < 4; ++mi)
#pragma unroll
            for (int ni = 0; ni < 4; ++ni)
                acc[mi][ni] = __builtin_amdgcn_mfma_f32_16x16x32_bf16(
                    a2[mi], b1[ni], acc[mi][ni], 0, 0, 0);
        __builtin_amdgcn_s_setprio(0);

        // ---- phase 3: kk1, mi 4-7 ----
        BARP;
        short8 a3[4];
#pragma unroll
        for (int mi = 0; mi < 4; ++mi) a3[mi] = *(const short8*)(Cb + a_off[4 + mi][1]);
        if (st) STAGE_B(b ^ 1, t + 1, 1);
        __builtin_amdgcn_s_setprio(1);
#pragma unroll
        for (int mi = 0; mi < 4; ++mi)
#pragma unroll
            for (int ni = 0; ni < 4; ++ni)
                acc[4 + mi][ni] = __builtin_amdgcn_mfma_f32_16x16x32_bf16(
                    a3[mi], b1[ni], acc[4 + mi][ni], 0, 0, 0);
        __builtin_amdgcn_s_setprio(0);
    }
#undef GATE4
#undef GATE0
#undef BARP

    // epilogue: D col = lane&15, row = (lane>>4)*4 + j
    float bias_n[4];
#pragma unroll
    for (int ni = 0; ni < 4; ++ni)
        bias_n[ni] = be[e * FN + n0 + wn * 64 + ni * 16 + frow];

    const int fq4 = fq * 4;
#pragma unroll
    for (int mi = 0; mi < 8; ++mi) {
        int rl = m0 + wm * 128 + mi * 16 + fq4;
#pragma unroll
        for (int j = 0; j < 4; ++j) {
            int idx = rl + j;
            if (idx < L) {
                float w = rw[s0 + idx];
                int oi = ridx[s0 + idx];
                if (MODE == 0) {
                    float* orow = out + (size_t)(oi >> 1) * FN + n0 + wn * 64 + frow;
#pragma unroll
                    for (int ni = 0; ni < 4; ++ni)
                        atomicAdd(orow + ni * 16, w * (acc[mi][ni][j] + bias_n[ni]));
                } else if (MODE == 1) {
                    unsigned short* yrow = (unsigned short*)ywv + (size_t)oi * FN + n0 + wn * 64 + frow;
#pragma unroll
                    for (int ni = 0; ni < 4; ++ni)
                        yrow[ni * 16] = f2bf(w * (acc[mi][ni][j] + bias_n[ni]));
                } else {
                    float* yrow = (float*)ywv + (size_t)oi * FN + n0 + wn * 64 + frow;
#pragma unroll
                    for (int ni = 0; ni < 4; ++ni)
                        yrow[ni * 16] = w * (acc[mi][ni][j] + bias_n[ni]);
                }
            }
        }
    }
}

// ---------------- combine: out[t] = yw[2t] + yw[2t+1] ------------------------
__global__ __launch_bounds__(256) void k_combine_bf(const unsigned short* __restrict__ yw,
                                                    float* __restrict__ out)
{
    int t = blockIdx.x;
    const short4v* r0 = (const short4v*)(yw + (size_t)(2 * t) * FN);
    const short4v* r1 = (const short4v*)(yw + (size_t)(2 * t + 1) * FN);
    f32x4* o = (f32x4*)(out + (size_t)t * FN);
    int i = threadIdx.x;
    short4v a = r0[i], b = r1[i];
    f32x4 v;
    v.x = bf2f((unsigned short)a.x) + bf2f((unsigned short)b.x);
    v.y = bf2f((unsigned short)a.y) + bf2f((unsigned short)b.y);
    v.z = bf2f((unsigned short)a.z) + bf2f((unsigned short)b.z);
    v.w = bf2f((unsigned short)a.w) + bf2f((unsigned short)b.w);
    o[i] = v;
}

__global__ __launch_bounds__(256) void k_combine_f32(const float* __restrict__ yw,
                                                     float* __restrict__ out)
{
    int t = blockIdx.x;
    const f32x4* r0 = (const f32x4*)(yw + (size_t)(2 * t) * FN);
    const f32x4* r1 = (const f32x4*)(yw + (size_t)(2 * t + 1) * FN);
    f32x4* o = (f32x4*)(out + (size_t)t * FN);
    int i = threadIdx.x;
    o[i] = r0[i] + r1[i];
}

extern "C" void kernel_launch(void* const* d_in, const int* in_sizes, int n_in,
                              void* d_out, int out_size, void* d_ws, size_t ws_size,
                              hipStream_t stream)
{
    const float* x   = (const float*)d_in[0];
    const float* We  = (const float*)d_in[1];
    const float* beb = (const float*)d_in[2];
    const float* Wg  = (const float*)d_in[3];
    const float* bg  = (const float*)d_in[4];
    float* out = (float*)d_out;

    char* ws = (char*)d_ws;
    unsigned short* xb = (unsigned short*)ws;                        // 16 MB
    unsigned short* Wb = (unsigned short*)(ws + (size_t)(16 << 20)); // 16 MB
    size_t off = (size_t)(32 << 20);
    int*   seg      = (int*)(ws + off);   off += 256;
    int*   blockcnt = (int*)(ws + off);   off += HB * NE * 4;
    int*   basebuf  = (int*)(ws + off);   off += HB * NE * 4;
    int*   meta_e   = (int*)(ws + off);   off += (size_t)NTOK * 2 * 4;
    float* meta_w   = (float*)(ws + off); off += (size_t)NTOK * 2 * 4;
    int*   ridxb    = (int*)(ws + off);   off += (size_t)NTOK * 2 * 4;
    float* rwb      = (float*)(ws + off); off += (size_t)NTOK * 2 * 4;
    void*  yw       = (void*)(ws + ((off + 255) & ~(size_t)255));
    size_t yw_base  = (size_t)((off + 255) & ~(size_t)255);

    // pick epilogue mode from available scratch (host-side, deterministic).
    int mode;
    if (ws_size >= yw_base + (size_t)NTOK * 2 * FN * 2) mode = 1;       // bf16 yw (32 MB)
    else if (ws_size >= yw_base + (size_t)NTOK * 2 * FN * 4) mode = 2;  // f32 yw (64 MB)
    else mode = 0;                                                      // atomic fallback

    k_gate<<<NTOK / 4, 256, 0, stream>>>(x, Wg, bg, xb, meta_e, meta_w);
    k_convw<<<(NE * FN * DK / 4) / 256, 256, 0, stream>>>(We, Wb);
    k_hist<<<HB, 256, 0, stream>>>(meta_e, blockcnt);
    k_scan<<<1, 64, 0, stream>>>(blockcnt, seg, basebuf);
    k_scatter<<<HB, 256, 0, stream>>>(meta_e, meta_w, basebuf, ridxb, rwb);

    const int nblk = NE * (FN / BN) * 32;   // 8 experts x 4 n-tiles x 32 m-tiles
    if (mode == 1) {
        k_gemm<1><<<nblk, 512, 0, stream>>>(xb, Wb, beb, seg, ridxb, rwb, out, yw);
        k_combine_bf<<<NTOK, 256, 0, stream>>>((const unsigned short*)yw, out);
    } else if (mode == 2) {
        k_gemm<2><<<nblk, 512, 0, stream>>>(xb, Wb, beb, seg, ridxb, rwb, out, yw);
        k_combine_f32<<<NTOK, 256, 0, stream>>>((const float*)yw, out);
    } else {
        hipMemsetAsync(d_out, 0, (size_t)NTOK * FN * 4, stream);
        k_gemm<0><<<nblk, 512, 0, stream>>>(xb, Wb, beb, seg, ridxb, rwb, out, yw);
    }
}

// Round 7
// 89.704 us; speedup vs baseline: 1.2698x; 1.2395x over previous
//
#include <hip/hip_runtime.h>
#include <hip/hip_bf16.h>
#include <stdint.h>

#define NE 8
#define DK 1024
#define FN 1024
#define NTOK 8192

#define BM 320
#define BN 256
#define BK 64
#define NIT (DK / BK)
#define MT 52            // max m-tiles per expert: ceil(16384/320)

#define HB 32
#define EPB (NTOK * 2 / HB)

// LDS map per buffer: A [320 rows x 128B] @0 (40960B), B-kh0 @40960 (16384B),
// B-kh1 @57344 (16384B); buffer stride 73728B; 2 buffers = 144KB.
#define BUFS 73728
#define BOFF 40960

typedef __attribute__((ext_vector_type(4))) float f32x4;
typedef __attribute__((ext_vector_type(8))) short short8;
typedef __attribute__((ext_vector_type(4))) short short4v;

__device__ __forceinline__ unsigned short f2bf(float f) {
    union { float f; unsigned u; } v; v.f = f;
    unsigned r = v.u;
    unsigned lsb = (r >> 16) & 1u;
    r += 0x7fffu + lsb;
    return (unsigned short)(r >> 16);
}
__device__ __forceinline__ float bf2f(unsigned short u) {
    union { unsigned u; float f; } v; v.u = ((unsigned)u) << 16;
    return v.f;
}

// ---------------- gating + x -> bf16 conversion (one wave per token) ---------
__global__ __launch_bounds__(256) void k_gate(const float* __restrict__ x,
    const float* __restrict__ Wg, const float* __restrict__ bg,
    unsigned short* __restrict__ xb, int* __restrict__ meta_e,
    float* __restrict__ meta_w)
{
    const int lane = threadIdx.x & 63;
    const int t = blockIdx.x * 4 + (threadIdx.x >> 6);

    const f32x4* xr = (const f32x4*)(x + (size_t)t * DK);
    f32x4 xv[4];
#pragma unroll
    for (int c = 0; c < 4; ++c) xv[c] = xr[lane + 64 * c];

    short4v* xbo = (short4v*)(xb + (size_t)t * DK);
#pragma unroll
    for (int c = 0; c < 4; ++c) {
        short4v b;
        b.x = (short)f2bf(xv[c].x); b.y = (short)f2bf(xv[c].y);
        b.z = (short)f2bf(xv[c].z); b.w = (short)f2bf(xv[c].w);
        xbo[lane + 64 * c] = b;
    }

    float acc[NE];
#pragma unroll
    for (int e = 0; e < NE; ++e) {
        const f32x4* wr = (const f32x4*)(Wg + e * DK);
        float a = 0.f;
#pragma unroll
        for (int c = 0; c < 4; ++c) {
            f32x4 wv = wr[lane + 64 * c];
            a += xv[c].x * wv.x + xv[c].y * wv.y + xv[c].z * wv.z + xv[c].w * wv.w;
        }
        acc[e] = a;
    }
#pragma unroll
    for (int e = 0; e < NE; ++e) {
        float a = acc[e];
#pragma unroll
        for (int off = 32; off > 0; off >>= 1) a += __shfl_xor(a, off, 64);
        acc[e] = a;
    }
    if (lane == 0) {
        float v[NE];
#pragma unroll
        for (int e = 0; e < NE; ++e) v[e] = acc[e] + bg[e];
        int b0 = 0; float m0 = v[0];
#pragma unroll
        for (int e = 1; e < NE; ++e) if (v[e] > m0) { m0 = v[e]; b0 = e; }
        int b1 = -1; float m1 = -3.4e38f;
#pragma unroll
        for (int e = 0; e < NE; ++e) if (e != b0 && v[e] > m1) { m1 = v[e]; b1 = e; }
        float r = expf(m1 - m0);
        float s = 1.f + r;
        meta_e[2 * t] = b0; meta_e[2 * t + 1] = b1;
        meta_w[2 * t] = 1.f / s; meta_w[2 * t + 1] = r / s;
    }
}

// ---------------- W -> bf16 ---------------------------------------------------
__global__ __launch_bounds__(256) void k_convw(const float* __restrict__ W,
                                               unsigned short* __restrict__ Wb)
{
    int i = blockIdx.x * 256 + threadIdx.x;
    f32x4 v = ((const f32x4*)W)[i];
    short4v b;
    b.x = (short)f2bf(v.x); b.y = (short)f2bf(v.y);
    b.z = (short)f2bf(v.z); b.w = (short)f2bf(v.w);
    ((short4v*)Wb)[i] = b;
}

// ---------------- per-block histogram (LDS atomics only) ---------------------
__global__ __launch_bounds__(256) void k_hist(const int* __restrict__ meta_e,
                                              int* __restrict__ blockcnt)
{
    __shared__ int lh[NE];
    if (threadIdx.x < NE) lh[threadIdx.x] = 0;
    __syncthreads();
    int base = blockIdx.x * EPB;
#pragma unroll
    for (int k = 0; k < EPB / 256; ++k)
        atomicAdd(&lh[meta_e[base + k * 256 + threadIdx.x]], 1);
    __syncthreads();
    if (threadIdx.x < NE) blockcnt[blockIdx.x * NE + threadIdx.x] = lh[threadIdx.x];
}

// ---------------- scan: expert segs + per-block bases ------------------------
__global__ void k_scan(const int* __restrict__ blockcnt, int* __restrict__ seg,
                       int* __restrict__ base)
{
    __shared__ int pre[HB][NE];
    __shared__ int colsum[NE];
    __shared__ int segstart[NE];
    int tid = threadIdx.x;
    if (tid < NE) {
        int run = 0;
        for (int b = 0; b < HB; ++b) { pre[b][tid] = run; run += blockcnt[b * NE + tid]; }
        colsum[tid] = run;
    }
    __syncthreads();
    if (tid == 0) {
        int s = 0;
        for (int e = 0; e < NE; ++e) { segstart[e] = s; seg[e] = s; s += colsum[e]; }
        seg[NE] = s;
    }
    __syncthreads();
    for (int i = tid; i < HB * NE; i += 64) {
        int b = i / NE, e = i % NE;
        base[i] = segstart[e] + pre[b][e];
    }
}

// ---------------- scatter: ridx[p] = 2t+k (orig slot), rw[p] = weight --------
__global__ __launch_bounds__(256) void k_scatter(const int* __restrict__ meta_e,
    const float* __restrict__ meta_w, const int* __restrict__ base,
    int* __restrict__ ridx, float* __restrict__ rw)
{
    __shared__ int lh[NE];
    __shared__ int bb[NE];
    if (threadIdx.x < NE) {
        lh[threadIdx.x] = 0;
        bb[threadIdx.x] = base[blockIdx.x * NE + threadIdx.x];
    }
    __syncthreads();
    int bs = blockIdx.x * EPB;
#pragma unroll
    for (int k = 0; k < EPB / 256; ++k) {
        int i = bs + k * 256 + threadIdx.x;
        int e = meta_e[i];
        int r = atomicAdd(&lh[e], 1);
        int p = bb[e] + r;
        ridx[p] = i;
        rw[p] = meta_w[i];
    }
}

// ---------------- grouped GEMM, 320x256, 4-phase counted-vmcnt ---------------
// 8 waves (2M x 4N), per-wave 160x64 output, acc[10][4].
// Single-round grid: ~224 survivor blocks (7 m-tiles/expert x 4 n x 8 e).
// Stage groups/tile: [A:5 instr @ph0][B-kh0:2 @ph1][B-kh1:2 @ph2] = 9.
// Gates: ph0 vmcnt(2) retires A(t)+B0(t); ph2 vmcnt(7) retires B1(t).
// 4-phase slack per group; drain only at last tile's ph2.
template <int MODE>
__global__ __launch_bounds__(512, 2) void k_gemm(const unsigned short* __restrict__ xb,
    const unsigned short* __restrict__ Wb, const float* __restrict__ be,
    const int* __restrict__ seg, const int* __restrict__ ridx,
    const float* __restrict__ rw, float* __restrict__ out, void* __restrict__ ywv)
{
    __shared__ char Lds[2 * BUFS];   // 144 KB

    const int bid = blockIdx.x;
    const int e = bid & 7;                       // XCD-pinned expert
    const int n0 = ((bid >> 3) & 3) * BN;
    const int mt = bid >> 5;
    const int s0 = seg[e];
    const int L = seg[e + 1] - s0;
    const int m0 = mt * BM;
    if (m0 >= L) return;

    const int tid = threadIdx.x;
    const int lane = tid & 63;
    const int wid = tid >> 6;
    const int wm = wid >> 2, wn = wid & 3;       // 2 x 4 wave grid

    // A staging: instr c covers rows c*64 + tid/8; granule g = (tid&7)^((tid>>3)&7)
    // (pre-swizzled source, linear LDS dest; read uses sl=(kk*4+fq)^(r&7))
    const int ag = ((tid & 7) ^ ((tid >> 3) & 7)) * 8;
    const unsigned short* asrc[5];
#pragma unroll
    for (int c = 0; c < 5; ++c) {
        int r = c * 64 + (tid >> 3);
        int idx = m0 + r; if (idx >= L) idx = L - 1;
        asrc[c] = xb + (size_t)(ridx[s0 + idx] >> 1) * DK + ag;
    }
    // B staging (kh halves): instr c covers rows c*128 + tid/4; granule
    // (tid&3)^((tid>>3)&3) within the 64B half-row (R6-verified layout)
    const int bgr = ((tid & 3) ^ ((tid >> 3) & 3)) * 8;
    const unsigned short* bsrc[2];
#pragma unroll
    for (int c = 0; c < 2; ++c) {
        int r = c * 128 + (tid >> 2);
        bsrc[c] = Wb + ((size_t)e * FN + n0 + r) * DK + bgr;
    }

    char* LB = (char*)Lds;

    f32x4 acc[10][4];
#pragma unroll
    for (int i = 0; i < 10; ++i)
#pragma unroll
        for (int j = 0; j < 4; ++j) acc[i][j] = f32x4{0.f, 0.f, 0.f, 0.f};

    const int frow = lane & 15;
    const int fq = lane >> 4;
    int a_off[10][2], b_off[4][2];
#pragma unroll
    for (int mi = 0; mi < 10; ++mi) {
        int r = wm * 160 + mi * 16 + frow;
#pragma unroll
        for (int kk = 0; kk < 2; ++kk)
            a_off[mi][kk] = r * 128 + (((kk * 4 + fq) ^ (r & 7)) * 16);
    }
#pragma unroll
    for (int ni = 0; ni < 4; ++ni) {
        int r = wn * 64 + ni * 16 + frow;
        int sl = fq ^ ((r >> 1) & 3);
#pragma unroll
        for (int kk = 0; kk < 2; ++kk)
            b_off[ni][kk] = BOFF + kk * 16384 + r * 64 + sl * 16;
    }

    auto STAGE_A = [&](int buf, int kt) {
        const int ko = kt * BK;
        char* dst = LB + buf * BUFS + wid * 1024;
#pragma unroll
        for (int c = 0; c < 5; ++c)
            __builtin_amdgcn_global_load_lds(
                (const __attribute__((address_space(1))) void*)(asrc[c] + ko),
                (__attribute__((address_space(3))) void*)(dst + c * 8192), 16, 0, 0);
    };
    auto STAGE_B = [&](int buf, int kt, int kh) {
        const int ko = kt * BK + kh * 32;
        char* dst = LB + buf * BUFS + BOFF + kh * 16384 + wid * 1024;
#pragma unroll
        for (int c = 0; c < 2; ++c)
            __builtin_amdgcn_global_load_lds(
                (const __attribute__((address_space(1))) void*)(bsrc[c] + ko),
                (__attribute__((address_space(3))) void*)(dst + c * 8192), 16, 0, 0);
    };

#define GATE2 do { asm volatile("s_waitcnt vmcnt(2)" ::: "memory"); \
                   __builtin_amdgcn_s_barrier(); \
                   __builtin_amdgcn_sched_barrier(0); } while (0)
#define GATE7 do { asm volatile("s_waitcnt vmcnt(7)" ::: "memory"); \
                   __builtin_amdgcn_s_barrier(); \
                   __builtin_amdgcn_sched_barrier(0); } while (0)
#define GATE0 do { asm volatile("s_waitcnt vmcnt(0)" ::: "memory"); \
                   __builtin_amdgcn_s_barrier(); \
                   __builtin_amdgcn_sched_barrier(0); } while (0)
#define BARP  do { __builtin_amdgcn_s_barrier(); \
                   __builtin_amdgcn_sched_barrier(0); } while (0)

    // 20 MFMA cluster: kk literal, 5 mi starting at mlo
#define CLUSTER(kk, mlo) do { \
    short8 bf4[4]; \
    _Pragma("unroll") \
    for (int ni = 0; ni < 4; ++ni) bf4[ni] = *(const short8*)(Cb + b_off[ni][kk]); \
    __builtin_amdgcn_s_setprio(1); \
    _Pragma("unroll") \
    for (int mi = (mlo); mi < (mlo) + 5; ++mi) { \
        short8 af = *(const short8*)(Cb + a_off[mi][kk]); \
        _Pragma("unroll") \
        for (int ni = 0; ni < 4; ++ni) \
            acc[mi][ni] = __builtin_amdgcn_mfma_f32_16x16x32_bf16( \
                af, bf4[ni], acc[mi][ni], 0, 0, 0); \
    } \
    __builtin_amdgcn_s_setprio(0); } while (0)

    // prologue: tile 0 -> buf 0 (A:5, B0:2, B1:2 = 9 outstanding, steady state)
    STAGE_A(0, 0); STAGE_B(0, 0, 0); STAGE_B(0, 0, 1);
    __builtin_amdgcn_sched_barrier(0);

    for (int t = 0; t < NIT; ++t) {
        const int b = t & 1;
        const char* Cb = LB + b * BUFS;
        const bool st = (t + 1 < NIT);

        // ph0: gate A(t)+B0(t); stage A(t+1); kk0 x mi 0-4
        GATE2;
        if (st) STAGE_A(b ^ 1, t + 1);
        CLUSTER(0, 0);

        // ph1: kk0 x mi 5-9; stage B0(t+1)
        BARP;
        if (st) STAGE_B(b ^ 1, t + 1, 0);
        CLUSTER(0, 5);

        // ph2: gate B1(t); stage B1(t+1); kk1 x mi 0-4
        if (st) { GATE7; } else { GATE0; }
        if (st) STAGE_B(b ^ 1, t + 1, 1);
        CLUSTER(1, 0);

        // ph3: kk1 x mi 5-9
        BARP;
        CLUSTER(1, 5);
    }
#undef GATE2
#undef GATE7
#undef GATE0
#undef BARP
#undef CLUSTER

    // epilogue: D col = lane&15, row = (lane>>4)*4 + j
    float bias_n[4];
#pragma unroll
    for (int ni = 0; ni < 4; ++ni)
        bias_n[ni] = be[e * FN + n0 + wn * 64 + ni * 16 + frow];

    const int fq4 = fq * 4;
#pragma unroll
    for (int mi = 0; mi < 10; ++mi) {
        int rl = m0 + wm * 160 + mi * 16 + fq4;
#pragma unroll
        for (int j = 0; j < 4; ++j) {
            int idx = rl + j;
            if (idx < L) {
                float w = rw[s0 + idx];
                int oi = ridx[s0 + idx];
                if (MODE == 0) {
                    float* orow = out + (size_t)(oi >> 1) * FN + n0 + wn * 64 + frow;
#pragma unroll
                    for (int ni = 0; ni < 4; ++ni)
                        atomicAdd(orow + ni * 16, w * (acc[mi][ni][j] + bias_n[ni]));
                } else if (MODE == 1) {
                    unsigned short* yrow = (unsigned short*)ywv + (size_t)oi * FN + n0 + wn * 64 + frow;
#pragma unroll
                    for (int ni = 0; ni < 4; ++ni)
                        yrow[ni * 16] = f2bf(w * (acc[mi][ni][j] + bias_n[ni]));
                } else {
                    float* yrow = (float*)ywv + (size_t)oi * FN + n0 + wn * 64 + frow;
#pragma unroll
                    for (int ni = 0; ni < 4; ++ni)
                        yrow[ni * 16] = w * (acc[mi][ni][j] + bias_n[ni]);
                }
            }
        }
    }
}

// ---------------- combine: out[t] = yw[2t] + yw[2t+1] ------------------------
__global__ __launch_bounds__(256) void k_combine_bf(const unsigned short* __restrict__ yw,
                                                    float* __restrict__ out)
{
    int t = blockIdx.x;
    const short4v* r0 = (const short4v*)(yw + (size_t)(2 * t) * FN);
    const short4v* r1 = (const short4v*)(yw + (size_t)(2 * t + 1) * FN);
    f32x4* o = (f32x4*)(out + (size_t)t * FN);
    int i = threadIdx.x;
    short4v a = r0[i], b = r1[i];
    f32x4 v;
    v.x = bf2f((unsigned short)a.x) + bf2f((unsigned short)b.x);
    v.y = bf2f((unsigned short)a.y) + bf2f((unsigned short)b.y);
    v.z = bf2f((unsigned short)a.z) + bf2f((unsigned short)b.z);
    v.w = bf2f((unsigned short)a.w) + bf2f((unsigned short)b.w);
    o[i] = v;
}

__global__ __launch_bounds__(256) void k_combine_f32(const float* __restrict__ yw,
                                                     float* __restrict__ out)
{
    int t = blockIdx.x;
    const f32x4* r0 = (const f32x4*)(yw + (size_t)(2 * t) * FN);
    const f32x4* r1 = (const f32x4*)(yw + (size_t)(2 * t + 1) * FN);
    f32x4* o = (f32x4*)(out + (size_t)t * FN);
    int i = threadIdx.x;
    o[i] = r0[i] + r1[i];
}

extern "C" void kernel_launch(void* const* d_in, const int* in_sizes, int n_in,
                              void* d_out, int out_size, void* d_ws, size_t ws_size,
                              hipStream_t stream)
{
    const float* x   = (const float*)d_in[0];
    const float* We  = (const float*)d_in[1];
    const float* beb = (const float*)d_in[2];
    const float* Wg  = (const float*)d_in[3];
    const float* bg  = (const float*)d_in[4];
    float* out = (float*)d_out;

    char* ws = (char*)d_ws;
    unsigned short* xb = (unsigned short*)ws;                        // 16 MB
    unsigned short* Wb = (unsigned short*)(ws + (size_t)(16 << 20)); // 16 MB
    size_t off = (size_t)(32 << 20);
    int*   seg      = (int*)(ws + off);   off += 256;
    int*   blockcnt = (int*)(ws + off);   off += HB * NE * 4;
    int*   basebuf  = (int*)(ws + off);   off += HB * NE * 4;
    int*   meta_e   = (int*)(ws + off);   off += (size_t)NTOK * 2 * 4;
    float* meta_w   = (float*)(ws + off); off += (size_t)NTOK * 2 * 4;
    int*   ridxb    = (int*)(ws + off);   off += (size_t)NTOK * 2 * 4;
    float* rwb      = (float*)(ws + off); off += (size_t)NTOK * 2 * 4;
    void*  yw       = (void*)(ws + ((off + 255) & ~(size_t)255));
    size_t yw_base  = (size_t)((off + 255) & ~(size_t)255);

    // pick epilogue mode from available scratch (host-side, deterministic).
    int mode;
    if (ws_size >= yw_base + (size_t)NTOK * 2 * FN * 2) mode = 1;       // bf16 yw (32 MB)
    else if (ws_size >= yw_base + (size_t)NTOK * 2 * FN * 4) mode = 2;  // f32 yw (64 MB)
    else mode = 0;                                                      // atomic fallback

    k_gate<<<NTOK / 4, 256, 0, stream>>>(x, Wg, bg, xb, meta_e, meta_w);
    k_convw<<<(NE * FN * DK / 4) / 256, 256, 0, stream>>>(We, Wb);
    k_hist<<<HB, 256, 0, stream>>>(meta_e, blockcnt);
    k_scan<<<1, 64, 0, stream>>>(blockcnt, seg, basebuf);
    k_scatter<<<HB, 256, 0, stream>>>(meta_e, meta_w, basebuf, ridxb, rwb);

    const int nblk = NE * (FN / BN) * MT;   // 8 experts x 4 n-tiles x 52 m-tiles
    if (mode == 1) {
        k_gemm<1><<<nblk, 512, 0, stream>>>(xb, Wb, beb, seg, ridxb, rwb, out, yw);
        k_combine_bf<<<NTOK, 256, 0, stream>>>((const unsigned short*)yw, out);
    } else if (mode == 2) {
        k_gemm<2><<<nblk, 512, 0, stream>>>(xb, Wb, beb, seg, ridxb, rwb, out, yw);
        k_combine_f32<<<NTOK, 256, 0, stream>>>((const float*)yw, out);
    } else {
        hipMemsetAsync(d_out, 0, (size_t)NTOK * FN * 4, stream);
        k_gemm<0><<<nblk, 512, 0, stream>>>(xb, Wb, beb, seg, ridxb, rwb, out, yw);
    }
}

// Round 8
// 87.942 us; speedup vs baseline: 1.2953x; 1.0200x over previous
//
#include <hip/hip_runtime.h>
#include <hip/hip_bf16.h>
#include <stdint.h>

#define NE 8
#define DK 1024
#define FN 1024
#define NTOK 8192

#define BM 320
#define BN 256
#define BK 64
#define NIT (DK / BK)
#define MT 52            // max m-tiles per expert: ceil(16384/320)

#define HB 32
#define EPB (NTOK * 2 / HB)

// LDS map per buffer: A [320 rows x 128B] @0 (40960B), B-kh0 @40960 (16384B),
// B-kh1 @57344 (16384B); buffer stride 73728B; 2 buffers = 144KB.
#define BUFS 73728
#define BOFF 40960

typedef __attribute__((ext_vector_type(4))) float f32x4;
typedef __attribute__((ext_vector_type(8))) short short8;
typedef __attribute__((ext_vector_type(4))) short short4v;

__device__ __forceinline__ unsigned short f2bf(float f) {
    union { float f; unsigned u; } v; v.f = f;
    unsigned r = v.u;
    unsigned lsb = (r >> 16) & 1u;
    r += 0x7fffu + lsb;
    return (unsigned short)(r >> 16);
}
__device__ __forceinline__ float bf2f(unsigned short u) {
    union { unsigned u; float f; } v; v.u = ((unsigned)u) << 16;
    return v.f;
}

// ---------------- gating + x -> bf16 conversion (one wave per token) ---------
__global__ __launch_bounds__(256) void k_gate(const float* __restrict__ x,
    const float* __restrict__ Wg, const float* __restrict__ bg,
    unsigned short* __restrict__ xb, int* __restrict__ meta_e,
    float* __restrict__ meta_w)
{
    const int lane = threadIdx.x & 63;
    const int t = blockIdx.x * 4 + (threadIdx.x >> 6);

    const f32x4* xr = (const f32x4*)(x + (size_t)t * DK);
    f32x4 xv[4];
#pragma unroll
    for (int c = 0; c < 4; ++c) xv[c] = xr[lane + 64 * c];

    short4v* xbo = (short4v*)(xb + (size_t)t * DK);
#pragma unroll
    for (int c = 0; c < 4; ++c) {
        short4v b;
        b.x = (short)f2bf(xv[c].x); b.y = (short)f2bf(xv[c].y);
        b.z = (short)f2bf(xv[c].z); b.w = (short)f2bf(xv[c].w);
        xbo[lane + 64 * c] = b;
    }

    float acc[NE];
#pragma unroll
    for (int e = 0; e < NE; ++e) {
        const f32x4* wr = (const f32x4*)(Wg + e * DK);
        float a = 0.f;
#pragma unroll
        for (int c = 0; c < 4; ++c) {
            f32x4 wv = wr[lane + 64 * c];
            a += xv[c].x * wv.x + xv[c].y * wv.y + xv[c].z * wv.z + xv[c].w * wv.w;
        }
        acc[e] = a;
    }
#pragma unroll
    for (int e = 0; e < NE; ++e) {
        float a = acc[e];
#pragma unroll
        for (int off = 32; off > 0; off >>= 1) a += __shfl_xor(a, off, 64);
        acc[e] = a;
    }
    if (lane == 0) {
        float v[NE];
#pragma unroll
        for (int e = 0; e < NE; ++e) v[e] = acc[e] + bg[e];
        int b0 = 0; float m0 = v[0];
#pragma unroll
        for (int e = 1; e < NE; ++e) if (v[e] > m0) { m0 = v[e]; b0 = e; }
        int b1 = -1; float m1 = -3.4e38f;
#pragma unroll
        for (int e = 0; e < NE; ++e) if (e != b0 && v[e] > m1) { m1 = v[e]; b1 = e; }
        float r = expf(m1 - m0);
        float s = 1.f + r;
        meta_e[2 * t] = b0; meta_e[2 * t + 1] = b1;
        meta_w[2 * t] = 1.f / s; meta_w[2 * t + 1] = r / s;
    }
}

// ---------------- W -> bf16 ---------------------------------------------------
__global__ __launch_bounds__(256) void k_convw(const float* __restrict__ W,
                                               unsigned short* __restrict__ Wb)
{
    int i = blockIdx.x * 256 + threadIdx.x;
    f32x4 v = ((const f32x4*)W)[i];
    short4v b;
    b.x = (short)f2bf(v.x); b.y = (short)f2bf(v.y);
    b.z = (short)f2bf(v.z); b.w = (short)f2bf(v.w);
    ((short4v*)Wb)[i] = b;
}

// ---------------- per-block histogram (LDS atomics only) ---------------------
__global__ __launch_bounds__(256) void k_hist(const int* __restrict__ meta_e,
                                              int* __restrict__ blockcnt)
{
    __shared__ int lh[NE];
    if (threadIdx.x < NE) lh[threadIdx.x] = 0;
    __syncthreads();
    int base = blockIdx.x * EPB;
#pragma unroll
    for (int k = 0; k < EPB / 256; ++k)
        atomicAdd(&lh[meta_e[base + k * 256 + threadIdx.x]], 1);
    __syncthreads();
    if (threadIdx.x < NE) blockcnt[blockIdx.x * NE + threadIdx.x] = lh[threadIdx.x];
}

// ---------------- scan: expert segs + per-block bases ------------------------
__global__ void k_scan(const int* __restrict__ blockcnt, int* __restrict__ seg,
                       int* __restrict__ base)
{
    __shared__ int pre[HB][NE];
    __shared__ int colsum[NE];
    __shared__ int segstart[NE];
    int tid = threadIdx.x;
    if (tid < NE) {
        int run = 0;
        for (int b = 0; b < HB; ++b) { pre[b][tid] = run; run += blockcnt[b * NE + tid]; }
        colsum[tid] = run;
    }
    __syncthreads();
    if (tid == 0) {
        int s = 0;
        for (int e = 0; e < NE; ++e) { segstart[e] = s; seg[e] = s; s += colsum[e]; }
        seg[NE] = s;
    }
    __syncthreads();
    for (int i = tid; i < HB * NE; i += 64) {
        int b = i / NE, e = i % NE;
        base[i] = segstart[e] + pre[b][e];
    }
}

// ---------------- scatter: ridx[p] = 2t+k (orig slot), rw[p] = weight --------
__global__ __launch_bounds__(256) void k_scatter(const int* __restrict__ meta_e,
    const float* __restrict__ meta_w, const int* __restrict__ base,
    int* __restrict__ ridx, float* __restrict__ rw)
{
    __shared__ int lh[NE];
    __shared__ int bb[NE];
    if (threadIdx.x < NE) {
        lh[threadIdx.x] = 0;
        bb[threadIdx.x] = base[blockIdx.x * NE + threadIdx.x];
    }
    __syncthreads();
    int bs = blockIdx.x * EPB;
#pragma unroll
    for (int k = 0; k < EPB / 256; ++k) {
        int i = bs + k * 256 + threadIdx.x;
        int e = meta_e[i];
        int r = atomicAdd(&lh[e], 1);
        int p = bb[e] + r;
        ridx[p] = i;
        rw[p] = meta_w[i];
    }
}

// ---------------- grouped GEMM, 320x256, 2-gate counted-vmcnt pipeline -------
// 8 waves (2M x 4N), per-wave 160x64, acc[10][4]. Per K-tile:
//   GATE2 -> {14 ds_read kk0 | STAGE A(t+1)+B0(t+1) | 40 MFMA}
//   GATE7 -> {14 ds_read kk1 | STAGE B1(t+1)        | 40 MFMA}
// In-order vmcnt retire proof: issue order per tile = [A:5,B0:2][B1:2].
// At GATE2(t): outstanding <= 9 (A,B0,B1 of t); vmcnt(2) retires A+B0.
// At GATE7(t): issued since = A,B0 of t+1 (7); <= 9 outstanding; vmcnt(7)
// retires B1(t), leaves t+1's 7 in flight. Last tile: GATE0.
// yw epilogue stores PERMUTED cols within each 64-block: col' = frow*4+ni
// (k_combine un-permutes; both yw rows share the permutation so add is safe).
template <int MODE>
__global__ __launch_bounds__(512, 2) void k_gemm(const unsigned short* __restrict__ xb,
    const unsigned short* __restrict__ Wb, const float* __restrict__ be,
    const int* __restrict__ seg, const int* __restrict__ ridx,
    const float* __restrict__ rw, float* __restrict__ out, void* __restrict__ ywv)
{
    __shared__ char Lds[2 * BUFS];   // 144 KB

    const int bid = blockIdx.x;
    const int e = bid & 7;                       // XCD-pinned expert
    const int n0 = ((bid >> 3) & 3) * BN;
    const int mt = bid >> 5;
    const int s0 = seg[e];
    const int L = seg[e + 1] - s0;
    const int m0 = mt * BM;
    if (m0 >= L) return;

    const int tid = threadIdx.x;
    const int lane = tid & 63;
    const int wid = tid >> 6;
    const int wm = wid >> 2, wn = wid & 3;       // 2 x 4 wave grid

    // A staging: instr c covers rows c*64 + tid/8; granule g = (tid&7)^((tid>>3)&7)
    const int ag = ((tid & 7) ^ ((tid >> 3) & 7)) * 8;
    const unsigned short* asrc[5];
#pragma unroll
    for (int c = 0; c < 5; ++c) {
        int r = c * 64 + (tid >> 3);
        int idx = m0 + r; if (idx >= L) idx = L - 1;
        asrc[c] = xb + (size_t)(ridx[s0 + idx] >> 1) * DK + ag;
    }
    // B staging (kh halves): instr c covers rows c*128 + tid/4
    const int bgr = ((tid & 3) ^ ((tid >> 3) & 3)) * 8;
    const unsigned short* bsrc[2];
#pragma unroll
    for (int c = 0; c < 2; ++c) {
        int r = c * 128 + (tid >> 2);
        bsrc[c] = Wb + ((size_t)e * FN + n0 + r) * DK + bgr;
    }

    char* LB = (char*)Lds;

    f32x4 acc[10][4];
#pragma unroll
    for (int i = 0; i < 10; ++i)
#pragma unroll
        for (int j = 0; j < 4; ++j) acc[i][j] = f32x4{0.f, 0.f, 0.f, 0.f};

    const int frow = lane & 15;
    const int fq = lane >> 4;
    int a_off[10][2], b_off[4][2];
#pragma unroll
    for (int mi = 0; mi < 10; ++mi) {
        int r = wm * 160 + mi * 16 + frow;
#pragma unroll
        for (int kk = 0; kk < 2; ++kk)
            a_off[mi][kk] = r * 128 + (((kk * 4 + fq) ^ (r & 7)) * 16);
    }
#pragma unroll
    for (int ni = 0; ni < 4; ++ni) {
        int r = wn * 64 + ni * 16 + frow;
        int sl = fq ^ ((r >> 1) & 3);
#pragma unroll
        for (int kk = 0; kk < 2; ++kk)
            b_off[ni][kk] = BOFF + kk * 16384 + r * 64 + sl * 16;
    }

    auto STAGE_A = [&](int buf, int kt) {
        const int ko = kt * BK;
        char* dst = LB + buf * BUFS + wid * 1024;
#pragma unroll
        for (int c = 0; c < 5; ++c)
            __builtin_amdgcn_global_load_lds(
                (const __attribute__((address_space(1))) void*)(asrc[c] + ko),
                (__attribute__((address_space(3))) void*)(dst + c * 8192), 16, 0, 0);
    };
    auto STAGE_B = [&](int buf, int kt, int kh) {
        const int ko = kt * BK + kh * 32;
        char* dst = LB + buf * BUFS + BOFF + kh * 16384 + wid * 1024;
#pragma unroll
        for (int c = 0; c < 2; ++c)
            __builtin_amdgcn_global_load_lds(
                (const __attribute__((address_space(1))) void*)(bsrc[c] + ko),
                (__attribute__((address_space(3))) void*)(dst + c * 8192), 16, 0, 0);
    };

#define GATE(N) do { asm volatile("s_waitcnt vmcnt(" #N ")" ::: "memory"); \
                     __builtin_amdgcn_s_barrier(); \
                     __builtin_amdgcn_sched_barrier(0); } while (0)

    // prologue: tile 0 -> buf 0 (A:5, B0:2, B1:2 = 9 outstanding)
    STAGE_A(0, 0); STAGE_B(0, 0, 0); STAGE_B(0, 0, 1);
    __builtin_amdgcn_sched_barrier(0);

    for (int t = 0; t < NIT; ++t) {
        const int b = t & 1;
        const char* Cb = LB + b * BUFS;
        const bool st = (t + 1 < NIT);

        // ---- half kk0: gate A(t)+B0(t) ----
        GATE(2);
        short8 b0f[4], a0f[10];
#pragma unroll
        for (int ni = 0; ni < 4; ++ni) b0f[ni] = *(const short8*)(Cb + b_off[ni][0]);
#pragma unroll
        for (int mi = 0; mi < 10; ++mi) a0f[mi] = *(const short8*)(Cb + a_off[mi][0]);
        if (st) { STAGE_A(b ^ 1, t + 1); STAGE_B(b ^ 1, t + 1, 0); }
        __builtin_amdgcn_s_setprio(1);
#pragma unroll
        for (int mi = 0; mi < 10; ++mi)
#pragma unroll
            for (int ni = 0; ni < 4; ++ni)
                acc[mi][ni] = __builtin_amdgcn_mfma_f32_16x16x32_bf16(
                    a0f[mi], b0f[ni], acc[mi][ni], 0, 0, 0);
        __builtin_amdgcn_s_setprio(0);

        // ---- half kk1: gate B1(t) ----
        if (st) { GATE(7); } else { GATE(0); }
        short8 b1f[4], a1f[10];
#pragma unroll
        for (int ni = 0; ni < 4; ++ni) b1f[ni] = *(const short8*)(Cb + b_off[ni][1]);
#pragma unroll
        for (int mi = 0; mi < 10; ++mi) a1f[mi] = *(const short8*)(Cb + a_off[mi][1]);
        if (st) STAGE_B(b ^ 1, t + 1, 1);
        __builtin_amdgcn_s_setprio(1);
#pragma unroll
        for (int mi = 0; mi < 10; ++mi)
#pragma unroll
            for (int ni = 0; ni < 4; ++ni)
                acc[mi][ni] = __builtin_amdgcn_mfma_f32_16x16x32_bf16(
                    a1f[mi], b1f[ni], acc[mi][ni], 0, 0, 0);
        __builtin_amdgcn_s_setprio(0);
    }
#undef GATE

    // epilogue: D col = lane&15, row = (lane>>4)*4 + j
    float bias_n[4];
#pragma unroll
    for (int ni = 0; ni < 4; ++ni)
        bias_n[ni] = be[e * FN + n0 + wn * 64 + ni * 16 + frow];

    const int fq4 = fq * 4;
#pragma unroll
    for (int mi = 0; mi < 10; ++mi) {
        int rl = m0 + wm * 160 + mi * 16 + fq4;
#pragma unroll
        for (int j = 0; j < 4; ++j) {
            int idx = rl + j;
            if (idx < L) {
                float w = rw[s0 + idx];
                int oi = ridx[s0 + idx];
                if (MODE == 0) {
                    float* orow = out + (size_t)(oi >> 1) * FN + n0 + wn * 64 + frow;
#pragma unroll
                    for (int ni = 0; ni < 4; ++ni)
                        atomicAdd(orow + ni * 16, w * (acc[mi][ni][j] + bias_n[ni]));
                } else if (MODE == 1) {
                    short4v pk;
                    pk.x = (short)f2bf(w * (acc[mi][0][j] + bias_n[0]));
                    pk.y = (short)f2bf(w * (acc[mi][1][j] + bias_n[1]));
                    pk.z = (short)f2bf(w * (acc[mi][2][j] + bias_n[2]));
                    pk.w = (short)f2bf(w * (acc[mi][3][j] + bias_n[3]));
                    *(short4v*)((unsigned short*)ywv + (size_t)oi * FN + n0 + wn * 64 + frow * 4) = pk;
                } else {
                    f32x4 pk;
                    pk.x = w * (acc[mi][0][j] + bias_n[0]);
                    pk.y = w * (acc[mi][1][j] + bias_n[1]);
                    pk.z = w * (acc[mi][2][j] + bias_n[2]);
                    pk.w = w * (acc[mi][3][j] + bias_n[3]);
                    *(f32x4*)((float*)ywv + (size_t)oi * FN + n0 + wn * 64 + frow * 4) = pk;
                }
            }
        }
    }
}

// ---------------- combine: out[t] = unperm(yw[2t] + yw[2t+1]) ----------------
// yw cols within each 64-block are permuted: col' = frow*4 + ni  (frow=c&15
// of true col c = wn*64 + ni*16 + frow). LDS pass un-permutes.
__global__ __launch_bounds__(256) void k_combine_bf(const unsigned short* __restrict__ yw,
                                                    float* __restrict__ out)
{
    __shared__ float ls[FN];
    int t = blockIdx.x, i = threadIdx.x;
    const unsigned* r0 = (const unsigned*)(yw + (size_t)(2 * t) * FN);
    const unsigned* r1 = (const unsigned*)(yw + (size_t)(2 * t + 1) * FN);
    unsigned a0 = r0[2 * i], a1 = r0[2 * i + 1];
    unsigned c0 = r1[2 * i], c1 = r1[2 * i + 1];
    float s0 = bf2f((unsigned short)(a0 & 0xffff)) + bf2f((unsigned short)(c0 & 0xffff));
    float s1 = bf2f((unsigned short)(a0 >> 16))    + bf2f((unsigned short)(c0 >> 16));
    float s2 = bf2f((unsigned short)(a1 & 0xffff)) + bf2f((unsigned short)(c1 & 0xffff));
    float s3 = bf2f((unsigned short)(a1 >> 16))    + bf2f((unsigned short)(c1 >> 16));
    int base = (i >> 4) * 64 + (i & 15);           // wn*64 + frow
    ls[base +  0] = s0;
    ls[base + 16] = s1;
    ls[base + 32] = s2;
    ls[base + 48] = s3;
    __syncthreads();
    ((f32x4*)(out + (size_t)t * FN))[i] = ((const f32x4*)ls)[i];
}

__global__ __launch_bounds__(256) void k_combine_f32(const float* __restrict__ yw,
                                                     float* __restrict__ out)
{
    __shared__ float ls[FN];
    int t = blockIdx.x, i = threadIdx.x;
    f32x4 a = ((const f32x4*)(yw + (size_t)(2 * t) * FN))[i];
    f32x4 b = ((const f32x4*)(yw + (size_t)(2 * t + 1) * FN))[i];
    f32x4 s = a + b;
    int base = (i >> 4) * 64 + (i & 15);
    ls[base +  0] = s.x;
    ls[base + 16] = s.y;
    ls[base + 32] = s.z;
    ls[base + 48] = s.w;
    __syncthreads();
    ((f32x4*)(out + (size_t)t * FN))[i] = ((const f32x4*)ls)[i];
}

extern "C" void kernel_launch(void* const* d_in, const int* in_sizes, int n_in,
                              void* d_out, int out_size, void* d_ws, size_t ws_size,
                              hipStream_t stream)
{
    const float* x   = (const float*)d_in[0];
    const float* We  = (const float*)d_in[1];
    const float* beb = (const float*)d_in[2];
    const float* Wg  = (const float*)d_in[3];
    const float* bg  = (const float*)d_in[4];
    float* out = (float*)d_out;

    char* ws = (char*)d_ws;
    unsigned short* xb = (unsigned short*)ws;                        // 16 MB
    unsigned short* Wb = (unsigned short*)(ws + (size_t)(16 << 20)); // 16 MB
    size_t off = (size_t)(32 << 20);
    int*   seg      = (int*)(ws + off);   off += 256;
    int*   blockcnt = (int*)(ws + off);   off += HB * NE * 4;
    int*   basebuf  = (int*)(ws + off);   off += HB * NE * 4;
    int*   meta_e   = (int*)(ws + off);   off += (size_t)NTOK * 2 * 4;
    float* meta_w   = (float*)(ws + off); off += (size_t)NTOK * 2 * 4;
    int*   ridxb    = (int*)(ws + off);   off += (size_t)NTOK * 2 * 4;
    float* rwb      = (float*)(ws + off); off += (size_t)NTOK * 2 * 4;
    void*  yw       = (void*)(ws + ((off + 255) & ~(size_t)255));
    size_t yw_base  = (size_t)((off + 255) & ~(size_t)255);

    // pick epilogue mode from available scratch (host-side, deterministic).
    int mode;
    if (ws_size >= yw_base + (size_t)NTOK * 2 * FN * 2) mode = 1;       // bf16 yw (32 MB)
    else if (ws_size >= yw_base + (size_t)NTOK * 2 * FN * 4) mode = 2;  // f32 yw (64 MB)
    else mode = 0;                                                      // atomic fallback

    k_gate<<<NTOK / 4, 256, 0, stream>>>(x, Wg, bg, xb, meta_e, meta_w);
    k_convw<<<(NE * FN * DK / 4) / 256, 256, 0, stream>>>(We, Wb);
    k_hist<<<HB, 256, 0, stream>>>(meta_e, blockcnt);
    k_scan<<<1, 64, 0, stream>>>(blockcnt, seg, basebuf);
    k_scatter<<<HB, 256, 0, stream>>>(meta_e, meta_w, basebuf, ridxb, rwb);

    const int nblk = NE * (FN / BN) * MT;   // 8 experts x 4 n-tiles x 52 m-tiles
    if (mode == 1) {
        k_gemm<1><<<nblk, 512, 0, stream>>>(xb, Wb, beb, seg, ridxb, rwb, out, yw);
        k_combine_bf<<<NTOK, 256, 0, stream>>>((const unsigned short*)yw, out);
    } else if (mode == 2) {
        k_gemm<2><<<nblk, 512, 0, stream>>>(xb, Wb, beb, seg, ridxb, rwb, out, yw);
        k_combine_f32<<<NTOK, 256, 0, stream>>>((const float*)yw, out);
    } else {
        hipMemsetAsync(d_out, 0, (size_t)NTOK * FN * 4, stream);
        k_gemm<0><<<nblk, 512, 0, stream>>>(xb, Wb, beb, seg, ridxb, rwb, out, yw);
    }
}